// Round 6
// baseline (455.709 us; speedup 1.0000x reference)
//
#include <hip/hip_runtime.h>
#include <stdint.h>

#define DIM 256
#define SEQ 8192
#define BATCH 32
#define QB 4                       // batches per eighth
#define QROWS (QB * SEQ)           // 32768
#define QCH 256                    // chunks per eighth
#define CS 128                     // chunk length == GEMM row tile
#define NCH (SEQ / CS)             // 64 chunks per sequence

typedef float f32x4 __attribute__((ext_vector_type(4)));
typedef short short8 __attribute__((ext_vector_type(8)));
typedef unsigned short u16;
typedef u16 ushort8 __attribute__((ext_vector_type(8)));
typedef u16 ushort4v __attribute__((ext_vector_type(4)));

__device__ __forceinline__ u16 f2bf(float f) {
  uint32_t u = __float_as_uint(f);
  u += 0x7fffu + ((u >> 16) & 1u);   // round-to-nearest-even
  return (u16)(u >> 16);
}
__device__ __forceinline__ float bf2f(uint32_t lo16) {
  return __uint_as_float(lo16 << 16);
}

// async 16B global->LDS (lds dest wave-uniform base; HW adds lane*16)
__device__ __forceinline__ void gld16(void* lds, const void* g) {
  __builtin_amdgcn_global_load_lds(
      (const __attribute__((address_space(1))) uint32_t*)g,
      (__attribute__((address_space(3))) uint32_t*)lds, 16, 0, 0);
}

// ---------- emb f32 -> bf16 table (one-time) ----------
__global__ void embq_kernel(const float* __restrict__ emb, u16* __restrict__ embq) {
  int i = (blockIdx.x * 256 + threadIdx.x) * 4;   // 8,192,000 elements
  float4 v = *(const float4*)(emb + i);
  ushort4v p;
  p[0] = f2bf(v.x); p[1] = f2bf(v.y); p[2] = f2bf(v.z); p[3] = f2bf(v.w);
  *(ushort4v*)(embq + i) = p;
}

// ---------- weight preprocess: f32 [l][k][d] -> bf16 swizzled 8KB tiles ----------
// WtS: 64 tiles of 8192 BYTES, tile index (mat*4 + dh)*4 + kt, in-tile [64 dloc][64 kl],
// byte = (dloc*128 + kl*2) ^ ((dloc&7)<<4).  mat: 0=Wz l0,1=Wz l1,2=Wh l0,3=Wh l1
__global__ void wt_kernel(const float* __restrict__ Wz, const float* __restrict__ Wh,
                          u16* __restrict__ WtS) {
  int idx = blockIdx.x * 256 + threadIdx.x;   // 4*65536
  int d = idx & 255;
  int k = (idx >> 8) & 255;
  int m = idx >> 16;
  const float* src = (m < 2 ? Wz : Wh) + (size_t)(m & 1) * 65536;
  float v = src[k * 256 + d];
  int dh = d >> 6, dloc = d & 63, kt = k >> 6, kl = k & 63;
  size_t tile = ((size_t)(m * 4 + dh) * 4 + kt) * 8192;   // BYTES
  size_t byte = (size_t)((dloc * 128 + kl * 2) ^ ((dloc & 7) << 4));
  *(u16*)((char*)WtS + tile + byte) = f2bf(v);
}

// ---------- GEMM + fused chunk-scan ----------
// Block: 128 rows (one chunk) x 128 d-slice (z + h), K=256, BK=64. grid=(QCH, 2).
// MODE 0: A = embq[x[row]] gather (reg-staged, swizzled ds_write); writes packed ab.
// MODE 1: A = h1q (pre-swizzled bf16 16KB tiles, global_load_lds verbatim).
template<int MODE>
__global__ __launch_bounds__(256, 2)
void gemm_kernel(const int* __restrict__ xq, const u16* __restrict__ embq,
                 const u16* __restrict__ h1q, const u16* __restrict__ WtS, int lsel,
                 const float* __restrict__ bzl, const float* __restrict__ bhl,
                 uint32_t* __restrict__ ab, float* __restrict__ Ap, float* __restrict__ Bs)
{
  __shared__ __align__(16) u16 As[8192];     // 16KB: [128 t][64 k] swizzled
  __shared__ __align__(16) u16 Bzs[8192];    // 16KB: 2 subtiles of 8KB ([64 d][64 k] swz)
  __shared__ __align__(16) u16 Bhs[8192];
  __shared__ float wtA[4][128], wtB[4][128];
  __shared__ int toks[128];

  const int tid = threadIdx.x;
  const int lane = tid & 63;
  const int w = tid >> 6;
  const int l15 = lane & 15, lg = lane >> 4;
  const int rows0 = blockIdx.x * 128;
  const int dh0 = blockIdx.y * 128;
  const int dhs = blockIdx.y * 2;            // first 64-d weight-tile index

  if (MODE == 0 && tid < 128) toks[tid] = xq[rows0 + tid];

  const char* bz0 = (const char*)WtS + (size_t)(lsel * 4 + dhs) * 4 * 8192;
  const char* bz1 = bz0 + 4 * 8192;
  const char* bh0 = (const char*)WtS + (size_t)((2 + lsel) * 4 + dhs) * 4 * 8192;
  const char* bh1 = bh0 + 4 * 8192;
  const char* amat = (MODE == 1) ? ((const char*)h1q + (size_t)blockIdx.x * 65536) : nullptr;

  f32x4 accz[2][8], acch[2][8];
  #pragma unroll
  for (int i = 0; i < 2; i++)
    #pragma unroll
    for (int j = 0; j < 8; j++) {
      f32x4 zz = {0.f, 0.f, 0.f, 0.f};
      accz[i][j] = zz; acch[i][j] = zz;
    }

  for (int kt = 0; kt < 4; kt++) {
    __syncthreads();
    // ---- stage B: 2 subtiles each of Bz, Bh (verbatim swizzled copies) ----
    {
      const char* gz = (w < 2 ? bz0 : bz1) + (size_t)kt * 8192 + (w & 1) * 4096;
      const char* gh = (w < 2 ? bh0 : bh1) + (size_t)kt * 8192 + (w & 1) * 4096;
      #pragma unroll
      for (int i = 0; i < 4; i++) {
        gld16((char*)Bzs + w * 4096 + i * 1024, gz + i * 1024 + lane * 16);
        gld16((char*)Bhs + w * 4096 + i * 1024, gh + i * 1024 + lane * 16);
      }
    }
    // ---- stage A ----
    if (MODE == 1) {
      const char* ga = amat + (size_t)kt * 16384;
      #pragma unroll
      for (int i = 0; i < 4; i++)
        gld16((char*)As + w * 4096 + i * 1024, ga + w * 4096 + i * 1024 + lane * 16);
    } else {
      const int sm = tid >> 1;
      const int skb = (tid & 1) * 64;           // byte offset of 32-short half
      const u16* arow = embq + (size_t)toks[sm] * 256 + kt * 64 + (tid & 1) * 32;
      #pragma unroll
      for (int j = 0; j < 4; j++) {
        ushort8 p = *(const ushort8*)(arow + j * 8);
        *(ushort8*)((char*)As + ((sm * 128 + skb + j * 16) ^ ((sm & 7) << 4))) = p;
      }
    }
    __syncthreads();

    // ---- compute: 2 k-substeps of 32 ----
    #pragma unroll
    for (int ks = 0; ks < 2; ks++) {
      const int xm = (l15 & 7) << 4;
      short8 fa[2];
      #pragma unroll
      for (int mi = 0; mi < 2; mi++)
        fa[mi] = *(const short8*)((const char*)As +
                   (((w * 32 + mi * 16 + l15) * 128 + ks * 64 + lg * 16) ^ xm));
      #pragma unroll
      for (int ni = 0; ni < 8; ni++) {
        const int sub = (ni >> 2) * 8192;
        const int off = (((ni & 3) * 16 + l15) * 128 + ks * 64 + lg * 16) ^ xm;
        short8 fbz = *(const short8*)((const char*)Bzs + sub + off);
        short8 fbh = *(const short8*)((const char*)Bhs + sub + off);
        #pragma unroll
        for (int mi = 0; mi < 2; mi++) {
          accz[mi][ni] = __builtin_amdgcn_mfma_f32_16x16x32_bf16(fa[mi], fbz, accz[mi][ni], 0, 0, 0);
          acch[mi][ni] = __builtin_amdgcn_mfma_f32_16x16x32_bf16(fa[mi], fbh, acch[mi][ni], 0, 0, 0);
        }
      }
    }
  }

  // ---- epilogue: gate + (MODE0) ab write + fused chunk compose ----
  #pragma unroll
  for (int ni = 0; ni < 8; ni++) {
    const int dloc = ni * 16 + l15;
    const float bzv = bzl[dh0 + dloc];
    const float bhv = bhl[dh0 + dloc];
    float At[2], Bt[2];
    #pragma unroll
    for (int mi = 0; mi < 2; mi++) {
      float A = 1.f, B = 0.f;
      #pragma unroll
      for (int r = 0; r < 4; r++) {
        float zl = accz[mi][ni][r] + bzv;
        float z = 1.f / (1.f + __expf(-zl));
        float ht = acch[mi][ni][r] + bhv;
        float a = 1.f - z, bb = z * ht;
        if (MODE == 0) {
          uint32_t pk = (uint32_t)f2bf(a) | ((uint32_t)f2bf(bb) << 16);
          ab[(size_t)(rows0 + w * 32 + mi * 16 + lg * 4 + r) * 256 + dh0 + dloc] = pk;
        }
        B = B * a + bb;
        A *= a;
      }
      At[mi] = A; Bt[mi] = B;
    }
    #pragma unroll
    for (int mi = 0; mi < 2; mi++) {
      float A = At[mi], B = Bt[mi];
      #pragma unroll
      for (int s = 16; s <= 32; s <<= 1) {
        float A2 = __shfl_xor(A, s);
        float B2 = __shfl_xor(B, s);
        if ((lane & s) == 0) { B = B * A2 + B2; A = A * A2; }
        else                 { B = B2 * A + B;  A = A2 * A; }
      }
      At[mi] = A; Bt[mi] = B;
    }
    float Aw = At[0] * At[1];
    float Bw = Bt[0] * At[1] + Bt[1];
    if (lg == 0) { wtA[w][dloc] = Aw; wtB[w][dloc] = Bw; }
  }
  __syncthreads();
  if (tid < 128) {
    float A = wtA[0][tid], B = wtB[0][tid];
    #pragma unroll
    for (int ww = 1; ww < 4; ww++) {
      float A2 = wtA[ww][tid], B2 = wtB[ww][tid];
      B = B * A2 + B2;
      A = A * A2;
    }
    const int idx = blockIdx.x * 256 + dh0 + tid;
    Ap[idx] = A; Bs[idx] = B;
  }
}

// ---------- layer-0 cross-chunk carries (per eighth: 4 batches) ----------
__global__ void scan2_l0(const float* __restrict__ Ap, const float* __restrict__ Bs,
                         float* __restrict__ carry) {
  const int b = blockIdx.x;            // 0..3
  const int d = threadIdx.x;           // 0..255
  float h = 0.f;
  for (int c = 0; c < NCH; c++) {
    const int idx = (b * NCH + c) * 256 + d;
    carry[idx] = h;
    h = Bs[idx] + Ap[idx] * h;
  }
}

// ---------- apply carries, write h1 as pre-swizzled bf16 16KB tiles ----------
// h1q: [chunk(QCH)][kt(4)] tiles of 16384 BYTES, byte = (t*128 + kl*2) ^ ((t&7)<<4)
__global__ void scan3_kernel(const uint32_t* __restrict__ ab, const float* __restrict__ carry,
                             u16* __restrict__ h1q) {
  const int blk = blockIdx.x;          // chunk in eighth
  const int td = threadIdx.x;          // 0..127 -> channel pair (2td, 2td+1)
  float h0 = carry[blk * 256 + 2 * td];
  float h1v = carry[blk * 256 + 2 * td + 1];
  const uint2* p = (const uint2*)ab + (size_t)blk * 16384 + td;
  char* tile = (char*)h1q + (size_t)blk * 65536 + (size_t)(td >> 5) * 16384;
  const int klb = (td & 31) * 4;
  #pragma unroll 8
  for (int t = 0; t < CS; t++) {
    uint2 v = p[(size_t)t * 128];
    float a0 = bf2f(v.x & 0xffffu), b0 = bf2f(v.x >> 16);
    float a1 = bf2f(v.y & 0xffffu), b1 = bf2f(v.y >> 16);
    h0 = a0 * h0 + b0;
    h1v = a1 * h1v + b1;
    uint32_t pk = (uint32_t)f2bf(h0) | ((uint32_t)f2bf(h1v) << 16);
    *(uint32_t*)(tile + ((t * 128 + klb) ^ ((t & 7) << 4))) = pk;
  }
}

// ---------- layer-1 final: serial over chunks -> hlast ----------
__global__ void scan2_l1(const float* __restrict__ Ap, const float* __restrict__ Bs,
                         float* __restrict__ hlast) {
  const int g = blockIdx.x * 256 + threadIdx.x;   // 8192 = 32 b * 256 d
  const int b = g >> 8, d = g & 255;
  float h = 0.f;
  for (int c = 0; c < NCH; c++) {
    const int idx = (b * NCH + c) * 256 + d;
    h = Bs[idx] + Ap[idx] * h;
  }
  hlast[b * 256 + d] = h;
}

__global__ void cls_kernel(const float* __restrict__ hlast, const float* __restrict__ Wo,
                           const float* __restrict__ bo, float* __restrict__ out) {
  const int t = threadIdx.x;       // 256 = 32 b * 8 classes
  const int b = t >> 3, c = t & 7;
  float acc = bo[c];
  for (int d = 0; d < DIM; d++) acc += hlast[b * 256 + d] * Wo[d * 8 + c];
  out[t] = acc;
}

extern "C" void kernel_launch(void* const* d_in, const int* in_sizes, int n_in,
                              void* d_out, int out_size, void* d_ws, size_t ws_size,
                              hipStream_t stream) {
  (void)in_sizes; (void)n_in; (void)out_size; (void)ws_size;
  const int*   x   = (const int*)d_in[0];
  const float* emb = (const float*)d_in[1];
  const float* Wz  = (const float*)d_in[2];
  const float* bz  = (const float*)d_in[3];
  const float* Wh  = (const float*)d_in[4];
  const float* bh  = (const float*)d_in[5];
  const float* Wo  = (const float*)d_in[6];
  const float* bo  = (const float*)d_in[7];
  float* out = (float*)d_out;
  char* ws = (char*)d_ws;

  // workspace layout (total ~72.6 MB; proven ws >= 174 MB)
  u16*      embq  = (u16*)     (ws);                        //  16,384,000
  uint32_t* ab    = (uint32_t*)(ws + 16777216ull);          //  33,554,432
  u16*      h1q   = (u16*)     (ws + 50331648ull);          //  16,777,216
  u16*      WtS   = (u16*)     (ws + 67108864ull);          //     524,288
  float*    Ap0   = (float*)   (ws + 67633152ull);          //     262,144
  float*    Bs0   = (float*)   (ws + 67895296ull);          //     262,144
  float*    carry = (float*)   (ws + 68157440ull);          //     262,144
  float*    Ap1   = (float*)   (ws + 68419584ull);          //   2,097,152
  float*    Bs1   = (float*)   (ws + 70516736ull);          //   2,097,152
  float*    hlast = (float*)   (ws + 72613888ull);          //      32,768

  embq_kernel<<<8000, 256, 0, stream>>>(emb, embq);
  wt_kernel<<<1024, 256, 0, stream>>>(Wz, Wh, WtS);

  for (int q = 0; q < 8; q++) {
    const int* xq = x + (size_t)q * QROWS;
    gemm_kernel<0><<<dim3(QCH, 2), 256, 0, stream>>>(
        xq, embq, nullptr, WtS, 0, bz, bh, ab, Ap0, Bs0);
    scan2_l0<<<QB, 256, 0, stream>>>(Ap0, Bs0, carry);
    scan3_kernel<<<QCH, 128, 0, stream>>>(ab, carry, h1q);
    gemm_kernel<1><<<dim3(QCH, 2), 256, 0, stream>>>(
        nullptr, nullptr, h1q, WtS, 1, bz + 256, bh + 256,
        nullptr, Ap1 + (size_t)q * (QCH * 256), Bs1 + (size_t)q * (QCH * 256));
  }

  scan2_l1<<<32, 256, 0, stream>>>(Ap1, Bs1, hlast);
  cls_kernel<<<1, 256, 0, stream>>>(hlast, Wo, bo, out);
}

// Round 7
// 367.667 us; speedup vs baseline: 1.2395x; 1.2395x over previous
//
#include <hip/hip_runtime.h>
#include <stdint.h>

#define SEQ 8192
#define HB 16                      // batches per half
#define HROWS (HB * SEQ)           // 131072 rows per half
#define HCH (HROWS / 128)          // 1024 chunks per half
#define CS 128                     // chunk length == GEMM row tile
#define NCH 64                     // chunks per sequence

typedef float f32x4 __attribute__((ext_vector_type(4)));
typedef short short8 __attribute__((ext_vector_type(8)));
typedef unsigned short u16;
typedef u16 ushort8 __attribute__((ext_vector_type(8)));
typedef u16 ushort4v __attribute__((ext_vector_type(4)));

__device__ __forceinline__ u16 f2bf(float f) {
  uint32_t u = __float_as_uint(f);
  u += 0x7fffu + ((u >> 16) & 1u);   // round-to-nearest-even
  return (u16)(u >> 16);
}
__device__ __forceinline__ float bf2f(uint32_t lo16) {
  return __uint_as_float(lo16 << 16);
}

// async 16B global->LDS (lds dest wave-uniform base; HW adds lane*16)
__device__ __forceinline__ void gld16(void* lds, const void* g) {
  __builtin_amdgcn_global_load_lds(
      (const __attribute__((address_space(1))) uint32_t*)g,
      (__attribute__((address_space(3))) uint32_t*)lds, 16, 0, 0);
}

// ---------- emb f32 -> bf16 table (one-time) ----------
__global__ void embq_kernel(const float* __restrict__ emb, u16* __restrict__ embq) {
  int i = (blockIdx.x * 256 + threadIdx.x) * 4;   // 8,192,000 elements
  float4 v = *(const float4*)(emb + i);
  ushort4v p;
  p[0] = f2bf(v.x); p[1] = f2bf(v.y); p[2] = f2bf(v.z); p[3] = f2bf(v.w);
  *(ushort4v*)(embq + i) = p;
}

// ---------- weight preprocess: f32 [l][k][d] -> bf16 swizzled 8KB tiles ----------
// WtS: 64 tiles of 8192 BYTES, tile index (mat*4 + dh)*4 + kt, in-tile [64 dloc][64 kl],
// byte = (dloc*128 + kl*2) ^ ((dloc&7)<<4).  mat: 0=Wz l0,1=Wz l1,2=Wh l0,3=Wh l1
__global__ void wt_kernel(const float* __restrict__ Wz, const float* __restrict__ Wh,
                          u16* __restrict__ WtS) {
  int idx = blockIdx.x * 256 + threadIdx.x;   // 4*65536
  int d = idx & 255;
  int k = (idx >> 8) & 255;
  int m = idx >> 16;
  const float* src = (m < 2 ? Wz : Wh) + (size_t)(m & 1) * 65536;
  float v = src[k * 256 + d];
  int dh = d >> 6, dloc = d & 63, kt = k >> 6, kl = k & 63;
  size_t tile = ((size_t)(m * 4 + dh) * 4 + kt) * 8192;   // BYTES
  size_t byte = (size_t)((dloc * 128 + kl * 2) ^ ((dloc & 7) << 4));
  *(u16*)((char*)WtS + tile + byte) = f2bf(v);
}

// ---------- unified GEMM + fused chunk-scan ----------
// Block: 512 threads (8 waves: 4 row-quads x 2 col-halves), 128 rows x 256 d (z+h), K=256.
// MODE 0 (layer 0): A = embq[x[row]] gather -> swizzled LDS; writes packed ab + chunk (A,B).
// MODE 1 (layer 1): A = h1 reconstructed IN LDS from ab+carry (fused scan3); chunk (A,B) out.
// As: 64KB [kt(4)][t(128)][kl(64)] swizzled; Bzs/Bhs: 32KB [dh(4)][64 d][64 kl] swizzled.
template<int MODE>
__global__ __launch_bounds__(512, 1)
void gemm_kernel(const int* __restrict__ xq, const u16* __restrict__ embq,
                 uint32_t* __restrict__ ab, const float* __restrict__ carry,
                 const u16* __restrict__ WtS,
                 const float* __restrict__ bzl, const float* __restrict__ bhl,
                 float* __restrict__ Ap, float* __restrict__ Bs, int chunk0)
{
  __shared__ __align__(16) u16 As[32768];
  __shared__ __align__(16) u16 Bzs[16384];
  __shared__ __align__(16) u16 Bhs[16384];
  __shared__ float wtA[4][256], wtB[4][256];

  const int tid = threadIdx.x;
  const int lane = tid & 63;
  const int w = tid >> 6;              // 0..7
  const int wr = w >> 1, wc = w & 1;   // wave grid: 4 row-quads x 2 col-halves
  const int l15 = lane & 15, lg = lane >> 4;
  const int rows0 = blockIdx.x * 128;
  const int lsel = MODE;               // layer select

  // ---- prologue: waves 4-7 stage B(kt=0); waves 0-3 build As ----
  if (w >= 4) {
    const int dh = w - 4;
    const char* gz = (const char*)WtS + (size_t)((lsel * 4 + dh) * 4 + 0) * 8192;
    const char* gh = (const char*)WtS + (size_t)(((2 + lsel) * 4 + dh) * 4 + 0) * 8192;
    #pragma unroll
    for (int i = 0; i < 8; i++) {
      gld16((char*)Bzs + dh * 8192 + i * 1024, gz + i * 1024 + lane * 16);
      gld16((char*)Bhs + dh * 8192 + i * 1024, gh + i * 1024 + lane * 16);
    }
  } else if (MODE == 0) {
    // gather one chunk of embeddings: thread = (row sm, k-half hb)
    const int sm = tid >> 1, hb = tid & 1;
    const int tok = xq[rows0 + sm];
    const u16* src = embq + (size_t)tok * 256 + hb * 128;
    char* sub = (char*)As + (size_t)(hb * 2) * 16384;
    const int swz = (sm & 7) << 4;
    #pragma unroll
    for (int j = 0; j < 16; j++) {
      ushort8 p = *(const ushort8*)(src + j * 8);
      const int kt_sub = j >> 3;            // 0/1 within this k-half
      const int kl2 = (j & 7) * 16;         // byte offset of kl within subtile row
      *(ushort8*)(sub + kt_sub * 16384 + ((sm * 128 + kl2) ^ swz)) = p;
    }
  } else {
    // fused scan3: reconstruct h for channel d over the chunk, write bf16 to LDS
    const int d = tid;                      // 0..255
    float h = carry[blockIdx.x * 256 + d];
    const uint32_t* p = ab + (size_t)rows0 * 256 + d;
    char* sub = (char*)As + (size_t)(d >> 6) * 16384;
    const int kl2 = (d & 63) * 2;
    #pragma unroll 8
    for (int t = 0; t < 128; t++) {
      uint32_t u = p[(size_t)t * 256];
      float a = bf2f(u & 0xffffu), bb = bf2f(u >> 16);
      h = a * h + bb;
      *(u16*)(sub + ((t * 128 + kl2) ^ ((t & 7) << 4))) = f2bf(h);
    }
  }

  f32x4 accz[2][8], acch[2][8];
  #pragma unroll
  for (int i = 0; i < 2; i++)
    #pragma unroll
    for (int j = 0; j < 8; j++) {
      f32x4 zz = {0.f, 0.f, 0.f, 0.f};
      accz[i][j] = zz; acch[i][j] = zz;
    }

  for (int kt = 0; kt < 4; kt++) {
    __syncthreads();                       // staging + As complete (drains vmcnt/lgkm)
    #pragma unroll
    for (int ks = 0; ks < 2; ks++) {
      const int xm = (l15 & 7) << 4;
      short8 fa[2];
      #pragma unroll
      for (int mi = 0; mi < 2; mi++)
        fa[mi] = *(const short8*)((const char*)As + kt * 16384 +
                   (((wr * 32 + mi * 16 + l15) * 128 + ks * 64 + lg * 16) ^ xm));
      #pragma unroll
      for (int ni = 0; ni < 8; ni++) {
        const int dh = wc * 2 + (ni >> 2);
        const int off = (((ni & 3) * 16 + l15) * 128 + ks * 64 + lg * 16) ^ xm;
        short8 fbz = *(const short8*)((const char*)Bzs + dh * 8192 + off);
        short8 fbh = *(const short8*)((const char*)Bhs + dh * 8192 + off);
        #pragma unroll
        for (int mi = 0; mi < 2; mi++) {
          accz[mi][ni] = __builtin_amdgcn_mfma_f32_16x16x32_bf16(fa[mi], fbz, accz[mi][ni], 0, 0, 0);
          acch[mi][ni] = __builtin_amdgcn_mfma_f32_16x16x32_bf16(fa[mi], fbh, acch[mi][ni], 0, 0, 0);
        }
      }
    }
    if (kt < 3) {
      __syncthreads();                     // B reads done before overwrite
      const int dh = w & 3;
      const char* g = (w < 4)
        ? (const char*)WtS + (size_t)((lsel * 4 + dh) * 4 + (kt + 1)) * 8192
        : (const char*)WtS + (size_t)(((2 + lsel) * 4 + dh) * 4 + (kt + 1)) * 8192;
      char* dst = (w < 4) ? (char*)Bzs + dh * 8192 : (char*)Bhs + dh * 8192;
      #pragma unroll
      for (int i = 0; i < 8; i++)
        gld16(dst + i * 1024, g + i * 1024 + lane * 16);
    }
  }

  // ---- epilogue: gate + (MODE0) ab write + fused chunk compose ----
  #pragma unroll
  for (int ni = 0; ni < 8; ni++) {
    const int dloc = wc * 128 + ni * 16 + l15;
    const float bzv = bzl[dloc];
    const float bhv = bhl[dloc];
    float At[2], Bt[2];
    #pragma unroll
    for (int mi = 0; mi < 2; mi++) {
      float A = 1.f, B = 0.f;
      #pragma unroll
      for (int r = 0; r < 4; r++) {
        float zl = accz[mi][ni][r] + bzv;
        float z = 1.f / (1.f + __expf(-zl));
        float ht = acch[mi][ni][r] + bhv;
        float a = 1.f - z, bb = z * ht;
        if (MODE == 0) {
          uint32_t pk = (uint32_t)f2bf(a) | ((uint32_t)f2bf(bb) << 16);
          ab[(size_t)(rows0 + wr * 32 + mi * 16 + lg * 4 + r) * 256 + dloc] = pk;
        }
        B = B * a + bb;
        A *= a;
      }
      At[mi] = A; Bt[mi] = B;
    }
    #pragma unroll
    for (int mi = 0; mi < 2; mi++) {
      float A = At[mi], B = Bt[mi];
      #pragma unroll
      for (int s = 16; s <= 32; s <<= 1) {
        float A2 = __shfl_xor(A, s);
        float B2 = __shfl_xor(B, s);
        if ((lane & s) == 0) { B = B * A2 + B2; A = A * A2; }
        else                 { B = B2 * A + B;  A = A2 * A; }
      }
      At[mi] = A; Bt[mi] = B;
    }
    float Aw = At[0] * At[1];
    float Bw = Bt[0] * At[1] + Bt[1];
    if (lg == 0) { wtA[wr][dloc] = Aw; wtB[wr][dloc] = Bw; }
  }
  __syncthreads();
  if (tid < 256) {
    float A = wtA[0][tid], B = wtB[0][tid];
    #pragma unroll
    for (int ww = 1; ww < 4; ww++) {
      float A2 = wtA[ww][tid], B2 = wtB[ww][tid];
      B = B * A2 + B2;
      A = A * A2;
    }
    const int idx = (chunk0 + blockIdx.x) * 256 + tid;
    Ap[idx] = A; Bs[idx] = B;
  }
}

// ---------- layer-0 cross-chunk carries (per half: 16 batches) ----------
__global__ void scan2_l0(const float* __restrict__ Ap, const float* __restrict__ Bs,
                         float* __restrict__ carry) {
  const int b = blockIdx.x;            // 0..15
  const int d = threadIdx.x;           // 0..255
  float h = 0.f;
  for (int c = 0; c < NCH; c++) {
    const int idx = (b * NCH + c) * 256 + d;
    carry[idx] = h;
    h = Bs[idx] + Ap[idx] * h;
  }
}

// ---------- layer-1 final: serial over chunks -> hlast ----------
__global__ void scan2_l1(const float* __restrict__ Ap, const float* __restrict__ Bs,
                         float* __restrict__ hlast) {
  const int g = blockIdx.x * 256 + threadIdx.x;   // 8192 = 32 b * 256 d
  const int b = g >> 8, d = g & 255;
  float h = 0.f;
  for (int c = 0; c < NCH; c++) {
    const int idx = (b * NCH + c) * 256 + d;
    h = Bs[idx] + Ap[idx] * h;
  }
  hlast[b * 256 + d] = h;
}

__global__ void cls_kernel(const float* __restrict__ hlast, const float* __restrict__ Wo,
                           const float* __restrict__ bo, float* __restrict__ out) {
  const int t = threadIdx.x;       // 256 = 32 b * 8 classes
  const int b = t >> 3, c = t & 7;
  float acc = bo[c];
  for (int d = 0; d < 256; d++) acc += hlast[b * 256 + d] * Wo[d * 8 + c];
  out[t] = acc;
}

extern "C" void kernel_launch(void* const* d_in, const int* in_sizes, int n_in,
                              void* d_out, int out_size, void* d_ws, size_t ws_size,
                              hipStream_t stream) {
  (void)in_sizes; (void)n_in; (void)out_size; (void)ws_size;
  const int*   x   = (const int*)d_in[0];
  const float* emb = (const float*)d_in[1];
  const float* Wz  = (const float*)d_in[2];
  const float* bz  = (const float*)d_in[3];
  const float* Wh  = (const float*)d_in[4];
  const float* bh  = (const float*)d_in[5];
  const float* Wo  = (const float*)d_in[6];
  const float* bo  = (const float*)d_in[7];
  float* out = (float*)d_out;
  char* ws = (char*)d_ws;

  // workspace layout (total ~158.9 MB; ws = 256 MiB confirmed)
  u16*      embq  = (u16*)     (ws);                        //  16,384,000
  uint32_t* ab    = (uint32_t*)(ws + 16777216ull);          // 134,217,728
  u16*      WtS   = (u16*)     (ws + 150994944ull);         //     524,288
  float*    Ap0   = (float*)   (ws + 151519232ull);         //   1,048,576
  float*    Bs0   = (float*)   (ws + 152567808ull);         //   1,048,576
  float*    carry = (float*)   (ws + 153616384ull);         //   1,048,576
  float*    Ap1   = (float*)   (ws + 154664960ull);         //   2,097,152
  float*    Bs1   = (float*)   (ws + 156762112ull);         //   2,097,152
  float*    hlast = (float*)   (ws + 158859264ull);         //      32,768

  embq_kernel<<<8000, 256, 0, stream>>>(emb, embq);
  wt_kernel<<<1024, 256, 0, stream>>>(Wz, Wh, WtS);

  for (int hf = 0; hf < 2; hf++) {
    const int* xq = x + (size_t)hf * HROWS;
    gemm_kernel<0><<<HCH, 512, 0, stream>>>(
        xq, embq, ab, nullptr, WtS, bz, bh, Ap0, Bs0, 0);
    scan2_l0<<<HB, 256, 0, stream>>>(Ap0, Bs0, carry);
    gemm_kernel<1><<<HCH, 512, 0, stream>>>(
        nullptr, nullptr, ab, carry, WtS, bz + 256, bh + 256,
        Ap1, Bs1, hf * HCH);
  }

  scan2_l1<<<32, 256, 0, stream>>>(Ap1, Bs1, hlast);
  cls_kernel<<<1, 256, 0, stream>>>(hlast, Wo, bo, out);
}